// Round 14
// baseline (212.743 us; speedup 1.0000x reference)
//
#include <hip/hip_runtime.h>
#include <hip/hip_bf16.h>
#include <stdint.h>

typedef unsigned short u16;
typedef short bf16x8 __attribute__((ext_vector_type(8)));
typedef float f32x4 __attribute__((ext_vector_type(4)));

#define DEVI static __device__ __forceinline__

#if __has_builtin(__builtin_amdgcn_exp2f)
#define EXP2F(x) __builtin_amdgcn_exp2f(x)
#else
#define EXP2F(x) exp2f(x)
#endif

DEVI u16 f2bf(float f) {
  union { float f; uint32_t u; } v; v.f = f;
  uint32_t u = v.u;
  u += 0x7fffu + ((u >> 16) & 1u);   // round-to-nearest-even
  return (u16)(u >> 16);
}
DEVI uint32_t pk2bf(float lo, float hi) {
  __hip_bfloat162 h = __float22bfloat162_rn(float2{lo, hi});
  union { __hip_bfloat162 h; uint32_t u; } v; v.h = h; return v.u;
}

DEVI void async16(const void* g, const void* l) {
  __builtin_amdgcn_global_load_lds(
      (const __attribute__((address_space(1))) void*)g,
      (__attribute__((address_space(3))) void*)l, 16, 0, 0);
}

DEVI f32x4 mfma16(bf16x8 a, bf16x8 b, f32x4 c) {
  return __builtin_amdgcn_mfma_f32_16x16x32_bf16(a, b, c, 0, 0, 0);
}

// ---------------------------------------------------------------- constants
// B=2, S=2048, H=1024, NH=16, D=64, M=B*S=4096
// log2(e)/sqrt(64): folded into Q at the qkv epilogue
#define CSC 0.18033688011112042f

// --------------------------- kernel 1: fused {fp32->bf16 x, W transpose}
__global__ void prep(const float* __restrict__ q, const float* __restrict__ k,
                     const float* __restrict__ v,
                     const float* __restrict__ Wq, const float* __restrict__ Wk,
                     const float* __restrict__ Wv, const float* __restrict__ Wo,
                     u16* __restrict__ XB, u16* __restrict__ WT) {
  __shared__ u16 tile[64 * 68];
  const int bid = blockIdx.x, t = threadIdx.x;
  if (bid < 12288) {
    const int z = bid >> 12, x = bid & 4095;
    const float* src = (z == 0) ? q : (z == 1) ? k : v;
    const int i = (x * 256 + t) * 4;
    float4 f = *(const float4*)(src + i);
    ushort4 o;
    o.x = f2bf(f.x); o.y = f2bf(f.y); o.z = f2bf(f.z); o.w = f2bf(f.w);
    *(ushort4*)(XB + (size_t)z * 4194304 + i) = o;
  } else {
    const int j = bid - 12288;               // 0..1023
    const int z = j >> 8, rem = j & 255;
    const float* W = (z == 0) ? Wq : (z == 1) ? Wk : (z == 2) ? Wv : Wo;
    u16* out = WT + (size_t)z * 1048576;
    const int R0 = (rem >> 4) * 64, C0 = (rem & 15) * 64;
#pragma unroll
    for (int it = 0; it < 16; ++it) {
      int jj = it * 256 + t;
      int r = jj >> 6, c = jj & 63;
      tile[r * 68 + c] = f2bf(W[(size_t)(R0 + r) * 1024 + C0 + c]);
    }
    __syncthreads();
#pragma unroll
    for (int it = 0; it < 16; ++it) {
      int jj = it * 256 + t;
      int c = jj >> 6, r = jj & 63;
      out[(size_t)(C0 + c) * 1024 + R0 + r] = tile[r * 68 + c];
    }
  }
}

// -------------------------------------------------- fused QKV projection GEMM
// R12 (resubmitted after infra failure): BK=32 RING-3 with issue-before-
// barrier + counted vmcnt. Ring-2's order gave stage(kt) only ~1 compute
// phase of latency cover. Ring-3 per iter:
//   issue(kt+1) into buf[(kt+1)%3]; vmcnt(4); s_barrier; compute buf[kt%3].
// Safety: issue(kt+1) overwrites the slot last used by compute(kt-2);
// the issuing wave passed barrier(kt-1) [collective] => all waves done
// with compute(kt-2); concurrent compute uses bufs (kt-1)%3 and kt%3,
// both != (kt+1)%3. vmcnt exact (4 loads/thread/stage, no other VMEM).
// LDS 3 x 16KB = 48KB -> (256,3): 768-block grid fully co-resident.
// Swizzle (BK=32): chunk = quad ^ ((row>>1)&3) -> 2 lanes/bank = free
// (m136); staging source pre-permuted to match (both-sides rule).
__global__ __launch_bounds__(256, 3)
void qkv_gemm(const u16* __restrict__ XB, const u16* __restrict__ WT,
              const float* __restrict__ bq, const float* __restrict__ bk,
              const float* __restrict__ bv,
              u16* __restrict__ QN, u16* __restrict__ KN, u16* __restrict__ VT) {
  __shared__ u16 smem[24576];   // 3-stage ring: s*8192 (lA 4096 + lB 4096); bounce aliases
  const int z = blockIdx.y;
  const u16* A  = XB + (size_t)z * 4194304;
  const u16* Bt = WT + (size_t)z * 1048576;
  const float* bias = (z == 0) ? bq : (z == 1) ? bk : bv;
  const int T = blockIdx.x;
  const int m0 = (T & 31) * 128, n0 = (T >> 5) * 128;
  const int t = threadIdx.x, lane = t & 63, w = t >> 6;
  const int quad = lane >> 4, l16 = lane & 15;
  const int wm = (w & 1) * 64, wn = (w >> 1) * 64;

  // per-stage: A 512 chunks + B 512 chunks; thread t covers {t, t+256} of each
#define QSTAGE32(k0, buf)                                                     \
  do {                                                                        \
    u16* lA_ = smem + (buf) * 8192;                                           \
    u16* lB_ = lA_ + 4096;                                                    \
    _Pragma("unroll")                                                         \
    for (int half = 0; half < 2; ++half) {                                    \
      int i = half * 256 + t;                                                 \
      int r = i >> 2, cc = i & 3, c = cc ^ ((r >> 1) & 3);                    \
      async16(A + (size_t)(m0 + r) * 1024 + (k0) + c * 8, &lA_[i * 8]);       \
      async16(Bt + (size_t)(n0 + r) * 1024 + (k0) + c * 8, &lB_[i * 8]);      \
    }                                                                         \
  } while (0)

  QSTAGE32(0, 0);   // prologue: stage 0 into buf 0

  f32x4 acc[4][4] = {};
  int cur = 0;
  for (int kt = 0; kt < 32; ++kt) {
    const int nxt = (cur == 2) ? 0 : cur + 1;
    if (kt + 1 < 32) {
      QSTAGE32((kt + 1) * 32, nxt);
      asm volatile("s_waitcnt vmcnt(4)" ::: "memory");
    } else {
      asm volatile("s_waitcnt vmcnt(0)" ::: "memory");
    }
    __builtin_amdgcn_s_barrier();
    __builtin_amdgcn_sched_barrier(0);
    const u16* lA = smem + cur * 8192;
    const u16* lB = lA + 4096;
    bf16x8 af[4], bfr[4];
#pragma unroll
    for (int rt = 0; rt < 4; ++rt) {
      int row = wm + rt * 16 + l16;
      af[rt] = *(const bf16x8*)&lA[row * 32 + (quad ^ ((row >> 1) & 3)) * 8];
    }
#pragma unroll
    for (int ct = 0; ct < 4; ++ct) {
      int row = wn + ct * 16 + l16;
      bfr[ct] = *(const bf16x8*)&lB[row * 32 + (quad ^ ((row >> 1) & 3)) * 8];
    }
    __builtin_amdgcn_s_setprio(1);
#pragma unroll
    for (int rt = 0; rt < 4; ++rt)
#pragma unroll
      for (int ct = 0; ct < 4; ++ct)
        acc[rt][ct] = mfma16(bfr[ct], af[rt], acc[rt][ct]);  // C^T: regs = d
    __builtin_amdgcn_s_setprio(0);
    cur = nxt;
  }
#undef QSTAGE32
  __syncthreads();   // ring dead; smem reusable as 128x132 bounce

  // ---- epilogue via LDS bounce
  if (z < 2) {
    const float scl = (z == 0) ? CSC : 1.0f;
#pragma unroll
    for (int rt = 0; rt < 4; ++rt) {
      int sl = wm + rt * 16 + l16;
#pragma unroll
      for (int ct = 0; ct < 4; ++ct) {
        int nb = wn + ct * 16 + quad * 4;
        float4 b4 = *(const float4*)&bias[n0 + nb];
        ushort4 pk;
        pk.x = f2bf((acc[rt][ct][0] + b4.x) * scl);
        pk.y = f2bf((acc[rt][ct][1] + b4.y) * scl);
        pk.z = f2bf((acc[rt][ct][2] + b4.z) * scl);
        pk.w = f2bf((acc[rt][ct][3] + b4.w) * scl);
        *(ushort4*)&smem[sl * 132 + nb] = pk;
      }
    }
    __syncthreads();
    u16* out = (z == 0) ? QN : KN;
#pragma unroll
    for (int p = 0; p < 8; ++p) {
      int idx = p * 256 + t;
      int row = idx >> 4, chunk = idx & 15;
      *(bf16x8*)&out[(size_t)(m0 + row) * 1024 + n0 + chunk * 8] =
          *(const bf16x8*)&smem[row * 132 + chunk * 8];
    }
  } else {
#pragma unroll
    for (int rt = 0; rt < 4; ++rt) {
      int sl = wm + rt * 16 + l16;
#pragma unroll
      for (int ct = 0; ct < 4; ++ct) {
        int nb = wn + ct * 16 + quad * 4;
        float4 b4 = *(const float4*)&bias[n0 + nb];
        smem[(nb + 0) * 132 + sl] = f2bf(acc[rt][ct][0] + b4.x);
        smem[(nb + 1) * 132 + sl] = f2bf(acc[rt][ct][1] + b4.y);
        smem[(nb + 2) * 132 + sl] = f2bf(acc[rt][ct][2] + b4.z);
        smem[(nb + 3) * 132 + sl] = f2bf(acc[rt][ct][3] + b4.w);
      }
    }
    __syncthreads();
    const int bb = m0 >> 11, sb = m0 & 2047;
#pragma unroll
    for (int p = 0; p < 8; ++p) {
      int idx = p * 256 + t;
      int dl = idx >> 4, chunk = idx & 15;
      int ncol = n0 + dl, hh = ncol >> 6, dd = ncol & 63;
      *(bf16x8*)&VT[((size_t)((bb * 16 + hh) * 64 + dd)) * 2048 + sb + chunk * 8] =
          *(const bf16x8*)&smem[dl * 132 + chunk * 8];
    }
  }
}

// -------------------------------------------------------- flash attention
// attn11 (best measured: 50.1-52.9us band). 2 K/V-tiles per barrier,
// 4-buffer ring, counted vmcnt, sigma-permuted K staging (P in registers),
// ones-MFMA row-sum, 512 thr / 8 waves x 16 q, grid (16,16,2), 2 blocks/CU.
__global__ __launch_bounds__(512, 4)
void attn11(const u16* __restrict__ QN, const u16* __restrict__ KN,
            const u16* __restrict__ VT, u16* __restrict__ AO) {
  __shared__ u16 lK[4][64 * 64];
  __shared__ u16 lV[4][64 * 64];
  const int qt0 = blockIdx.x, h = blockIdx.y, b = blockIdx.z;
  const int t = threadIdx.x, lane = t & 63, w = t >> 6;
  const int quad = lane >> 4, l16 = lane & 15;
  const u16* Qg = QN + ((size_t)(b * 2048 + qt0 * 128)) * 1024 + h * 64;
  const u16* Kg = KN + ((size_t)b * 2048) * 1024 + h * 64;
  const u16* Vg = VT + ((size_t)((b * 16 + h) * 64)) * 2048;

  // sigma(r): bit4<-bit3, bit3<-bit2, bit2<-bit4 (bits 5,1,0 fixed)
  const int sr_r = t >> 3;
  const int sg_r = (sr_r & 0x23) | ((sr_r & 8) << 1) | ((sr_r & 4) << 1) |
                   ((sr_r & 16) >> 2);
  const int sc_c = (t & 7) ^ (sr_r & 7);

  bf16x8 qf[2];
#pragma unroll
  for (int ks = 0; ks < 2; ++ks)
    qf[ks] = *(const bf16x8*)(Qg + (size_t)(w * 16 + l16) * 1024 + ks * 32 + quad * 8);

  const bf16x8 ones = {0x3F80, 0x3F80, 0x3F80, 0x3F80,
                       0x3F80, 0x3F80, 0x3F80, 0x3F80};

  async16(Kg + (size_t)sg_r * 1024 + sc_c * 8, &lK[0][t * 8]);
  async16(Vg + (size_t)sr_r * 2048 + sc_c * 8, &lV[0][t * 8]);
  async16(Kg + (size_t)(64 + sg_r) * 1024 + sc_c * 8, &lK[1][t * 8]);
  async16(Vg + (size_t)sr_r * 2048 + 64 + sc_c * 8, &lV[1][t * 8]);

  f32x4 o[4] = {};
  f32x4 ls = {};

  for (int it = 0; it < 16; ++it) {
    const int ta = it * 2;
    asm volatile("s_waitcnt vmcnt(0)" ::: "memory");
    __builtin_amdgcn_s_barrier();
    __builtin_amdgcn_sched_barrier(0);

    if (it + 1 < 16) {
      const int kb0 = (ta + 2) * 64, nb0 = (ta + 2) & 3;
      async16(Kg + (size_t)(kb0 + sg_r) * 1024 + sc_c * 8, &lK[nb0][t * 8]);
      async16(Vg + (size_t)sr_r * 2048 + kb0 + sc_c * 8, &lV[nb0][t * 8]);
      const int kb1 = (ta + 3) * 64, nb1 = (ta + 3) & 3;
      async16(Kg + (size_t)(kb1 + sg_r) * 1024 + sc_c * 8, &lK[nb1][t * 8]);
      async16(Vg + (size_t)sr_r * 2048 + kb1 + sc_c * 8, &lV[nb1][t * 8]);
    }

    f32x4 sc2[2][4];
    __builtin_amdgcn_s_setprio(1);
#pragma unroll
    for (int u = 0; u < 2; ++u) {
      const u16* Kc = &lK[(ta + u) & 3][0];
#pragma unroll
      for (int st = 0; st < 4; ++st) {
        int row = st * 16 + l16;
        bf16x8 kf0 = *(const bf16x8*)&Kc[row * 64 + ((quad) ^ (row & 7)) * 8];
        bf16x8 kf1 = *(const bf16x8*)&Kc[row * 64 + ((4 + quad) ^ (row & 7)) * 8];
        f32x4 z = {};
        sc2[u][st] = mfma16(kf0, qf[0], z);
        sc2[u][st] = mfma16(kf1, qf[1], sc2[u][st]);
      }
    }
    __builtin_amdgcn_s_setprio(0);

#pragma unroll
    for (int u = 0; u < 2; ++u) {
      union { uint32_t uw[4]; bf16x8 v; } p0, p1;
#pragma unroll
      for (int st = 0; st < 2; ++st) {
        p0.uw[st * 2 + 0] = pk2bf(EXP2F(sc2[u][st][0]), EXP2F(sc2[u][st][1]));
        p0.uw[st * 2 + 1] = pk2bf(EXP2F(sc2[u][st][2]), EXP2F(sc2[u][st][3]));
        p1.uw[st * 2 + 0] = pk2bf(EXP2F(sc2[u][2 + st][0]), EXP2F(sc2[u][2 + st][1]));
        p1.uw[st * 2 + 1] = pk2bf(EXP2F(sc2[u][2 + st][2]), EXP2F(sc2[u][2 + st][3]));
      }
      __builtin_amdgcn_s_setprio(1);
      ls = mfma16(ones, p0.v, ls);
      ls = mfma16(ones, p1.v, ls);
      const u16* Vc = &lV[(ta + u) & 3][0];
#pragma unroll
      for (int dt = 0; dt < 4; ++dt) {
        int row = dt * 16 + l16;
        bf16x8 vf0 = *(const bf16x8*)&Vc[row * 64 + ((quad) ^ (row & 7)) * 8];
        bf16x8 vf1 = *(const bf16x8*)&Vc[row * 64 + ((4 + quad) ^ (row & 7)) * 8];
        o[dt] = mfma16(vf0, p0.v, o[dt]);
        o[dt] = mfma16(vf1, p1.v, o[dt]);
      }
      __builtin_amdgcn_s_setprio(0);
    }
  }

  float inv = 1.0f / ls[0];
  int qglob = qt0 * 128 + w * 16 + l16;
  size_t base = ((size_t)(b * 2048 + qglob)) * 1024 + h * 64;
#pragma unroll
  for (int dt = 0; dt < 4; ++dt) {
    ushort4 pk;
    pk.x = f2bf(o[dt][0] * inv);
    pk.y = f2bf(o[dt][1] * inv);
    pk.z = f2bf(o[dt][2] * inv);
    pk.w = f2bf(o[dt][3] * inv);
    *(ushort4*)&AO[base + dt * 16 + quad * 4] = pk;
  }
}

// ------------------------------------------------------- output projection
// R12 (resubmitted): BK=32 RING-3 (same mechanism as qkv) + (256,4):
// 3 stages x 12KB = 36KB -> 4 blocks/CU = 16 waves/CU. 3 loads/thread/
// stage -> steady vmcnt(3). 128m x 64n tiles, 512 blocks, XCD swizzle.
__global__ __launch_bounds__(256, 4)
void oproj_gemm(const u16* __restrict__ AO, const u16* __restrict__ Bt,
                const float* __restrict__ bias, float* __restrict__ out) {
  __shared__ u16 smem[18432];   // 3 stages x (lA 4096 + lB 2048) u16
  const int T = blockIdx.x;
  const int m0 = (T & 31) * 128, n0 = (T >> 5) * 64;
  const int t = threadIdx.x, lane = t & 63, w = t >> 6;
  const int quad = lane >> 4, l16 = lane & 15;
  const int wm = (w & 1) * 64, wn = (w >> 1) * 32;

#define OSTAGE32(k0, buf)                                                     \
  do {                                                                        \
    u16* lA_ = smem + (buf) * 6144;                                           \
    u16* lB_ = lA_ + 4096;                                                    \
    _Pragma("unroll")                                                         \
    for (int half = 0; half < 2; ++half) {                                    \
      int i = half * 256 + t;                                                 \
      int r = i >> 2, cc = i & 3, c = cc ^ ((r >> 1) & 3);                    \
      async16(AO + (size_t)(m0 + r) * 1024 + (k0) + c * 8, &lA_[i * 8]);      \
    }                                                                         \
    {                                                                         \
      int r = t >> 2, cc = t & 3, c = cc ^ ((r >> 1) & 3);                    \
      async16(Bt + (size_t)(n0 + r) * 1024 + (k0) + c * 8, &lB_[t * 8]);      \
    }                                                                         \
  } while (0)

  OSTAGE32(0, 0);   // prologue: stage 0 into buf 0

  f32x4 acc[4][2] = {};
  int cur = 0;
  for (int kt = 0; kt < 32; ++kt) {
    const int nxt = (cur == 2) ? 0 : cur + 1;
    if (kt + 1 < 32) {
      OSTAGE32((kt + 1) * 32, nxt);
      asm volatile("s_waitcnt vmcnt(3)" ::: "memory");
    } else {
      asm volatile("s_waitcnt vmcnt(0)" ::: "memory");
    }
    __builtin_amdgcn_s_barrier();
    __builtin_amdgcn_sched_barrier(0);
    const u16* lA = smem + cur * 6144;
    const u16* lB = lA + 4096;
    bf16x8 af[4], bfr[2];
#pragma unroll
    for (int rt = 0; rt < 4; ++rt) {
      int row = wm + rt * 16 + l16;
      af[rt] = *(const bf16x8*)&lA[row * 32 + (quad ^ ((row >> 1) & 3)) * 8];
    }
#pragma unroll
    for (int ct = 0; ct < 2; ++ct) {
      int row = wn + ct * 16 + l16;
      bfr[ct] = *(const bf16x8*)&lB[row * 32 + (quad ^ ((row >> 1) & 3)) * 8];
    }
    __builtin_amdgcn_s_setprio(1);
#pragma unroll
    for (int rt = 0; rt < 4; ++rt)
#pragma unroll
      for (int ct = 0; ct < 2; ++ct)
        acc[rt][ct] = mfma16(af[rt], bfr[ct], acc[rt][ct]);
    __builtin_amdgcn_s_setprio(0);
    cur = nxt;
  }
#undef OSTAGE32

#pragma unroll
  for (int ct = 0; ct < 2; ++ct) {
    int ncol = n0 + wn + ct * 16 + l16;
    float bvv = bias[ncol];
#pragma unroll
    for (int rt = 0; rt < 4; ++rt)
#pragma unroll
      for (int r = 0; r < 4; ++r) {
        int m = m0 + wm + rt * 16 + quad * 4 + r;
        out[(size_t)m * 1024 + ncol] = acc[rt][ct][r] + bvv;
      }
  }
}

// ------------------------------------------------------------------ launch
extern "C" void kernel_launch(void* const* d_in, const int* in_sizes, int n_in,
                              void* d_out, int out_size, void* d_ws, size_t ws_size,
                              hipStream_t stream) {
  const float* query = (const float*)d_in[0];
  const float* key   = (const float*)d_in[1];
  const float* value = (const float*)d_in[2];
  const float* Wq = (const float*)d_in[3];
  const float* bq = (const float*)d_in[4];
  const float* Wk = (const float*)d_in[5];
  const float* bk = (const float*)d_in[6];
  const float* Wv = (const float*)d_in[7];
  const float* bv = (const float*)d_in[8];
  const float* Wo = (const float*)d_in[9];
  const float* bo = (const float*)d_in[10];
  float* out = (float*)d_out;

  // workspace layout (u16 elements): total 28M u16 = 56 MB
  u16* WT = (u16*)d_ws;              // 4 x 1M  (Wq_t, Wk_t, Wv_t, Wo_t)
  u16* QN = WT + 4 * 1048576;        // 4M  natural [b,s,1024] (pre-scaled by CSC)
  u16* KN = QN + 4194304;            // 4M  natural [b,s,1024]
  u16* VT = KN + 4194304;            // 4M  [b,h,d,s]
  u16* XB = VT + 4194304;            // 3 x 4M bf16 copies of q,k,v
  u16* AO = XB;                      // attn out aliases XB (dead by then)

  prep<<<dim3(13312), 256, 0, stream>>>(query, key, value, Wq, Wk, Wv, Wo, XB, WT);
  qkv_gemm<<<dim3(256, 3), 256, 0, stream>>>(XB, WT, bq, bk, bv, QN, KN, VT);
  attn11<<<dim3(16, 16, 2), 512, 0, stream>>>(QN, KN, VT, AO);
  oproj_gemm<<<dim3(512), 256, 0, stream>>>(AO, WT + 3 * 1048576, bo, out);
}

// Round 15
// 201.912 us; speedup vs baseline: 1.0536x; 1.0536x over previous
//
#include <hip/hip_runtime.h>
#include <hip/hip_bf16.h>
#include <stdint.h>

typedef unsigned short u16;
typedef short bf16x8 __attribute__((ext_vector_type(8)));
typedef float f32x4 __attribute__((ext_vector_type(4)));

#define DEVI static __device__ __forceinline__

#if __has_builtin(__builtin_amdgcn_exp2f)
#define EXP2F(x) __builtin_amdgcn_exp2f(x)
#else
#define EXP2F(x) exp2f(x)
#endif

DEVI u16 f2bf(float f) {
  union { float f; uint32_t u; } v; v.f = f;
  uint32_t u = v.u;
  u += 0x7fffu + ((u >> 16) & 1u);   // round-to-nearest-even
  return (u16)(u >> 16);
}
DEVI uint32_t pk2bf(float lo, float hi) {
  __hip_bfloat162 h = __float22bfloat162_rn(float2{lo, hi});
  union { __hip_bfloat162 h; uint32_t u; } v; v.h = h; return v.u;
}

DEVI void async16(const void* g, const void* l) {
  __builtin_amdgcn_global_load_lds(
      (const __attribute__((address_space(1))) void*)g,
      (__attribute__((address_space(3))) void*)l, 16, 0, 0);
}

DEVI f32x4 mfma16(bf16x8 a, bf16x8 b, f32x4 c) {
  return __builtin_amdgcn_mfma_f32_16x16x32_bf16(a, b, c, 0, 0, 0);
}

// ---------------------------------------------------------------- constants
// B=2, S=2048, H=1024, NH=16, D=64, M=B*S=4096
// log2(e)/sqrt(64): folded into Q at the qkv epilogue
#define CSC 0.18033688011112042f

// --------------------------- kernel 1: fused {fp32->bf16 x, W transpose}
__global__ void prep(const float* __restrict__ q, const float* __restrict__ k,
                     const float* __restrict__ v,
                     const float* __restrict__ Wq, const float* __restrict__ Wk,
                     const float* __restrict__ Wv, const float* __restrict__ Wo,
                     u16* __restrict__ XB, u16* __restrict__ WT) {
  __shared__ u16 tile[64 * 68];
  const int bid = blockIdx.x, t = threadIdx.x;
  if (bid < 12288) {
    const int z = bid >> 12, x = bid & 4095;
    const float* src = (z == 0) ? q : (z == 1) ? k : v;
    const int i = (x * 256 + t) * 4;
    float4 f = *(const float4*)(src + i);
    ushort4 o;
    o.x = f2bf(f.x); o.y = f2bf(f.y); o.z = f2bf(f.z); o.w = f2bf(f.w);
    *(ushort4*)(XB + (size_t)z * 4194304 + i) = o;
  } else {
    const int j = bid - 12288;               // 0..1023
    const int z = j >> 8, rem = j & 255;
    const float* W = (z == 0) ? Wq : (z == 1) ? Wk : (z == 2) ? Wv : Wo;
    u16* out = WT + (size_t)z * 1048576;
    const int R0 = (rem >> 4) * 64, C0 = (rem & 15) * 64;
#pragma unroll
    for (int it = 0; it < 16; ++it) {
      int jj = it * 256 + t;
      int r = jj >> 6, c = jj & 63;
      tile[r * 68 + c] = f2bf(W[(size_t)(R0 + r) * 1024 + C0 + c]);
    }
    __syncthreads();
#pragma unroll
    for (int it = 0; it < 16; ++it) {
      int jj = it * 256 + t;
      int c = jj >> 6, r = jj & 63;
      out[(size_t)(C0 + c) * 1024 + R0 + r] = tile[r * 68 + c];
    }
  }
}

// ---- staging helper (attn11-proven ring order: vmcnt->barrier->issue->compute)
DEVI void qstage(const u16* __restrict__ A, const u16* __restrict__ Bt,
                 u16* lA, u16* lB, int m0, int n0, int k0, int t) {
#pragma unroll
  for (int it = 0; it < 4; ++it) {
    int i = it * 256 + t;
    int r = i >> 3, cc = i & 7, c = cc ^ (r & 7);
    async16(A + (size_t)(m0 + r) * 1024 + k0 + c * 8, &lA[i * 8]);
    async16(Bt + (size_t)(n0 + r) * 1024 + k0 + c * 8, &lB[i * 8]);
  }
}

// -------------------------------------------------- fused QKV projection GEMM
// R11-measured-best (204.0us total): BK=64 RING-2 double buffer.
// Per kt: vmcnt(0) [loads issued a full compute-phase ago] -> s_barrier ->
// issue kt+1 into buf[(kt+1)&1] (=buf[kt-1]; all waves provably past
// compute(kt-1) at the barrier) -> compute buf[kt&1]. One barrier/kt.
// R12/R14 post-mortem: BK=32 (ring-2 206.9, ring-3 212.7) BOTH regress —
// fewer, fatter stages win (32 MFMA per barrier amortizes convergence).
// LDS 2x32KB=64KB -> 2 blocks/CU; epilogue bounce aliases ring.
__global__ __launch_bounds__(256, 2)
void qkv_gemm(const u16* __restrict__ XB, const u16* __restrict__ WT,
              const float* __restrict__ bq, const float* __restrict__ bk,
              const float* __restrict__ bv,
              u16* __restrict__ QN, u16* __restrict__ KN, u16* __restrict__ VT) {
  __shared__ u16 smem[32768];   // ring buf b at +b*16384 (lA 8192, lB 8192 u16)
  const int z = blockIdx.y;
  const u16* A  = XB + (size_t)z * 4194304;
  const u16* Bt = WT + (size_t)z * 1048576;
  const float* bias = (z == 0) ? bq : (z == 1) ? bk : bv;
  const int T = blockIdx.x;
  const int m0 = (T & 31) * 128, n0 = (T >> 5) * 128;
  const int t = threadIdx.x, lane = t & 63, w = t >> 6;
  const int quad = lane >> 4, l16 = lane & 15;
  const int wm = (w & 1) * 64, wn = (w >> 1) * 64;

  qstage(A, Bt, smem, smem + 8192, m0, n0, 0, t);   // prologue: tile 0

  f32x4 acc[4][4] = {};
  for (int kt = 0; kt < 16; ++kt) {
    asm volatile("s_waitcnt vmcnt(0)" ::: "memory");
    __builtin_amdgcn_s_barrier();
    __builtin_amdgcn_sched_barrier(0);
    if (kt + 1 < 16) {
      u16* nb = smem + ((kt + 1) & 1) * 16384;
      qstage(A, Bt, nb, nb + 8192, m0, n0, (kt + 1) * 64, t);
    }
    const u16* lA = smem + (kt & 1) * 16384;
    const u16* lB = lA + 8192;
#pragma unroll
    for (int ks = 0; ks < 2; ++ks) {
      bf16x8 af[4], bfr[4];
#pragma unroll
      for (int rt = 0; rt < 4; ++rt) {
        int row = wm + rt * 16 + l16;
        af[rt] = *(const bf16x8*)&lA[row * 64 + ((ks * 4 + quad) ^ (row & 7)) * 8];
      }
#pragma unroll
      for (int ct = 0; ct < 4; ++ct) {
        int row = wn + ct * 16 + l16;
        bfr[ct] = *(const bf16x8*)&lB[row * 64 + ((ks * 4 + quad) ^ (row & 7)) * 8];
      }
      __builtin_amdgcn_s_setprio(1);
#pragma unroll
      for (int rt = 0; rt < 4; ++rt)
#pragma unroll
        for (int ct = 0; ct < 4; ++ct)
          acc[rt][ct] = mfma16(bfr[ct], af[rt], acc[rt][ct]);  // C^T: regs = d
      __builtin_amdgcn_s_setprio(0);
    }
  }
  __syncthreads();   // ring dead; smem reusable as 128x132 bounce

  // ---- epilogue via LDS bounce
  if (z < 2) {
    const float scl = (z == 0) ? CSC : 1.0f;
#pragma unroll
    for (int rt = 0; rt < 4; ++rt) {
      int sl = wm + rt * 16 + l16;
#pragma unroll
      for (int ct = 0; ct < 4; ++ct) {
        int nb = wn + ct * 16 + quad * 4;
        float4 b4 = *(const float4*)&bias[n0 + nb];
        ushort4 pk;
        pk.x = f2bf((acc[rt][ct][0] + b4.x) * scl);
        pk.y = f2bf((acc[rt][ct][1] + b4.y) * scl);
        pk.z = f2bf((acc[rt][ct][2] + b4.z) * scl);
        pk.w = f2bf((acc[rt][ct][3] + b4.w) * scl);
        *(ushort4*)&smem[sl * 132 + nb] = pk;
      }
    }
    __syncthreads();
    u16* out = (z == 0) ? QN : KN;
#pragma unroll
    for (int p = 0; p < 8; ++p) {
      int idx = p * 256 + t;
      int row = idx >> 4, chunk = idx & 15;
      *(bf16x8*)&out[(size_t)(m0 + row) * 1024 + n0 + chunk * 8] =
          *(const bf16x8*)&smem[row * 132 + chunk * 8];
    }
  } else {
#pragma unroll
    for (int rt = 0; rt < 4; ++rt) {
      int sl = wm + rt * 16 + l16;
#pragma unroll
      for (int ct = 0; ct < 4; ++ct) {
        int nb = wn + ct * 16 + quad * 4;
        float4 b4 = *(const float4*)&bias[n0 + nb];
        smem[(nb + 0) * 132 + sl] = f2bf(acc[rt][ct][0] + b4.x);
        smem[(nb + 1) * 132 + sl] = f2bf(acc[rt][ct][1] + b4.y);
        smem[(nb + 2) * 132 + sl] = f2bf(acc[rt][ct][2] + b4.z);
        smem[(nb + 3) * 132 + sl] = f2bf(acc[rt][ct][3] + b4.w);
      }
    }
    __syncthreads();
    const int bb = m0 >> 11, sb = m0 & 2047;
#pragma unroll
    for (int p = 0; p < 8; ++p) {
      int idx = p * 256 + t;
      int dl = idx >> 4, chunk = idx & 15;
      int ncol = n0 + dl, hh = ncol >> 6, dd = ncol & 63;
      *(bf16x8*)&VT[((size_t)((bb * 16 + hh) * 64 + dd)) * 2048 + sb + chunk * 8] =
          *(const bf16x8*)&smem[dl * 132 + chunk * 8];
    }
  }
}

// -------------------------------------------------------- flash attention
// attn11 (best measured: 49.9-52.9us band). 2 K/V-tiles per barrier,
// 4-buffer ring, counted vmcnt, sigma-permuted K staging (P in registers),
// ones-MFMA row-sum, 512 thr / 8 waves x 16 q, grid (16,16,2), 2 blocks/CU.
__global__ __launch_bounds__(512, 4)
void attn11(const u16* __restrict__ QN, const u16* __restrict__ KN,
            const u16* __restrict__ VT, u16* __restrict__ AO) {
  __shared__ u16 lK[4][64 * 64];
  __shared__ u16 lV[4][64 * 64];
  const int qt0 = blockIdx.x, h = blockIdx.y, b = blockIdx.z;
  const int t = threadIdx.x, lane = t & 63, w = t >> 6;
  const int quad = lane >> 4, l16 = lane & 15;
  const u16* Qg = QN + ((size_t)(b * 2048 + qt0 * 128)) * 1024 + h * 64;
  const u16* Kg = KN + ((size_t)b * 2048) * 1024 + h * 64;
  const u16* Vg = VT + ((size_t)((b * 16 + h) * 64)) * 2048;

  // sigma(r): bit4<-bit3, bit3<-bit2, bit2<-bit4 (bits 5,1,0 fixed)
  const int sr_r = t >> 3;
  const int sg_r = (sr_r & 0x23) | ((sr_r & 8) << 1) | ((sr_r & 4) << 1) |
                   ((sr_r & 16) >> 2);
  const int sc_c = (t & 7) ^ (sr_r & 7);

  bf16x8 qf[2];
#pragma unroll
  for (int ks = 0; ks < 2; ++ks)
    qf[ks] = *(const bf16x8*)(Qg + (size_t)(w * 16 + l16) * 1024 + ks * 32 + quad * 8);

  const bf16x8 ones = {0x3F80, 0x3F80, 0x3F80, 0x3F80,
                       0x3F80, 0x3F80, 0x3F80, 0x3F80};

  async16(Kg + (size_t)sg_r * 1024 + sc_c * 8, &lK[0][t * 8]);
  async16(Vg + (size_t)sr_r * 2048 + sc_c * 8, &lV[0][t * 8]);
  async16(Kg + (size_t)(64 + sg_r) * 1024 + sc_c * 8, &lK[1][t * 8]);
  async16(Vg + (size_t)sr_r * 2048 + 64 + sc_c * 8, &lV[1][t * 8]);

  f32x4 o[4] = {};
  f32x4 ls = {};

  for (int it = 0; it < 16; ++it) {
    const int ta = it * 2;
    asm volatile("s_waitcnt vmcnt(0)" ::: "memory");
    __builtin_amdgcn_s_barrier();
    __builtin_amdgcn_sched_barrier(0);

    if (it + 1 < 16) {
      const int kb0 = (ta + 2) * 64, nb0 = (ta + 2) & 3;
      async16(Kg + (size_t)(kb0 + sg_r) * 1024 + sc_c * 8, &lK[nb0][t * 8]);
      async16(Vg + (size_t)sr_r * 2048 + kb0 + sc_c * 8, &lV[nb0][t * 8]);
      const int kb1 = (ta + 3) * 64, nb1 = (ta + 3) & 3;
      async16(Kg + (size_t)(kb1 + sg_r) * 1024 + sc_c * 8, &lK[nb1][t * 8]);
      async16(Vg + (size_t)sr_r * 2048 + kb1 + sc_c * 8, &lV[nb1][t * 8]);
    }

    f32x4 sc2[2][4];
    __builtin_amdgcn_s_setprio(1);
#pragma unroll
    for (int u = 0; u < 2; ++u) {
      const u16* Kc = &lK[(ta + u) & 3][0];
#pragma unroll
      for (int st = 0; st < 4; ++st) {
        int row = st * 16 + l16;
        bf16x8 kf0 = *(const bf16x8*)&Kc[row * 64 + ((quad) ^ (row & 7)) * 8];
        bf16x8 kf1 = *(const bf16x8*)&Kc[row * 64 + ((4 + quad) ^ (row & 7)) * 8];
        f32x4 z = {};
        sc2[u][st] = mfma16(kf0, qf[0], z);
        sc2[u][st] = mfma16(kf1, qf[1], sc2[u][st]);
      }
    }
    __builtin_amdgcn_s_setprio(0);

#pragma unroll
    for (int u = 0; u < 2; ++u) {
      union { uint32_t uw[4]; bf16x8 v; } p0, p1;
#pragma unroll
      for (int st = 0; st < 2; ++st) {
        p0.uw[st * 2 + 0] = pk2bf(EXP2F(sc2[u][st][0]), EXP2F(sc2[u][st][1]));
        p0.uw[st * 2 + 1] = pk2bf(EXP2F(sc2[u][st][2]), EXP2F(sc2[u][st][3]));
        p1.uw[st * 2 + 0] = pk2bf(EXP2F(sc2[u][2 + st][0]), EXP2F(sc2[u][2 + st][1]));
        p1.uw[st * 2 + 1] = pk2bf(EXP2F(sc2[u][2 + st][2]), EXP2F(sc2[u][2 + st][3]));
      }
      __builtin_amdgcn_s_setprio(1);
      ls = mfma16(ones, p0.v, ls);
      ls = mfma16(ones, p1.v, ls);
      const u16* Vc = &lV[(ta + u) & 3][0];
#pragma unroll
      for (int dt = 0; dt < 4; ++dt) {
        int row = dt * 16 + l16;
        bf16x8 vf0 = *(const bf16x8*)&Vc[row * 64 + ((quad) ^ (row & 7)) * 8];
        bf16x8 vf1 = *(const bf16x8*)&Vc[row * 64 + ((4 + quad) ^ (row & 7)) * 8];
        o[dt] = mfma16(vf0, p0.v, o[dt]);
        o[dt] = mfma16(vf1, p1.v, o[dt]);
      }
      __builtin_amdgcn_s_setprio(0);
    }
  }

  float inv = 1.0f / ls[0];
  int qglob = qt0 * 128 + w * 16 + l16;
  size_t base = ((size_t)(b * 2048 + qglob)) * 1024 + h * 64;
#pragma unroll
  for (int dt = 0; dt < 4; ++dt) {
    ushort4 pk;
    pk.x = f2bf(o[dt][0] * inv);
    pk.y = f2bf(o[dt][1] * inv);
    pk.z = f2bf(o[dt][2] * inv);
    pk.w = f2bf(o[dt][3] * inv);
    *(ushort4*)&AO[base + dt * 16 + quad * 4] = pk;
  }
}

// ------------------------------------------------------- output projection
// R11-measured-best: BK=64 RING-2 (same order as qkv). 128m x 64n tiles,
// 512 blocks, XCD swizzle (m_tile = T&31). LDS 2x24KB=48KB -> 3 blocks/CU.
__global__ __launch_bounds__(256, 3)
void oproj_gemm(const u16* __restrict__ AO, const u16* __restrict__ Bt,
                const float* __restrict__ bias, float* __restrict__ out) {
  __shared__ u16 smem[24576];   // ring buf b at +b*12288 (lA 8192, lB 4096 u16)
  const int T = blockIdx.x;
  const int m0 = (T & 31) * 128, n0 = (T >> 5) * 64;
  const int t = threadIdx.x, lane = t & 63, w = t >> 6;
  const int quad = lane >> 4, l16 = lane & 15;
  const int wm = (w & 1) * 64, wn = (w >> 1) * 32;

  // prologue: tile 0
  {
    u16* lA = smem; u16* lB = smem + 8192;
#pragma unroll
    for (int it = 0; it < 4; ++it) {
      int i = it * 256 + t;
      int r = i >> 3, cc = i & 7, c = cc ^ (r & 7);
      async16(AO + (size_t)(m0 + r) * 1024 + c * 8, &lA[i * 8]);
    }
#pragma unroll
    for (int it = 0; it < 2; ++it) {
      int i = it * 256 + t;
      int r = i >> 3, cc = i & 7, c = cc ^ (r & 7);
      async16(Bt + (size_t)(n0 + r) * 1024 + c * 8, &lB[i * 8]);
    }
  }

  f32x4 acc[4][2] = {};
  for (int kt = 0; kt < 16; ++kt) {
    asm volatile("s_waitcnt vmcnt(0)" ::: "memory");
    __builtin_amdgcn_s_barrier();
    __builtin_amdgcn_sched_barrier(0);
    if (kt + 1 < 16) {
      const int k0 = (kt + 1) * 64;
      u16* lA = smem + ((kt + 1) & 1) * 12288;
      u16* lB = lA + 8192;
#pragma unroll
      for (int it = 0; it < 4; ++it) {
        int i = it * 256 + t;
        int r = i >> 3, cc = i & 7, c = cc ^ (r & 7);
        async16(AO + (size_t)(m0 + r) * 1024 + k0 + c * 8, &lA[i * 8]);
      }
#pragma unroll
      for (int it = 0; it < 2; ++it) {
        int i = it * 256 + t;
        int r = i >> 3, cc = i & 7, c = cc ^ (r & 7);
        async16(Bt + (size_t)(n0 + r) * 1024 + k0 + c * 8, &lB[i * 8]);
      }
    }
    const u16* lA = smem + (kt & 1) * 12288;
    const u16* lB = lA + 8192;
#pragma unroll
    for (int ks = 0; ks < 2; ++ks) {
      bf16x8 af[4], bfr[2];
#pragma unroll
      for (int rt = 0; rt < 4; ++rt) {
        int row = wm + rt * 16 + l16;
        af[rt] = *(const bf16x8*)&lA[row * 64 + ((ks * 4 + quad) ^ (row & 7)) * 8];
      }
#pragma unroll
      for (int ct = 0; ct < 2; ++ct) {
        int row = wn + ct * 16 + l16;
        bfr[ct] = *(const bf16x8*)&lB[row * 64 + ((ks * 4 + quad) ^ (row & 7)) * 8];
      }
      __builtin_amdgcn_s_setprio(1);
#pragma unroll
      for (int rt = 0; rt < 4; ++rt)
#pragma unroll
        for (int ct = 0; ct < 2; ++ct)
          acc[rt][ct] = mfma16(af[rt], bfr[ct], acc[rt][ct]);
      __builtin_amdgcn_s_setprio(0);
    }
  }

#pragma unroll
  for (int ct = 0; ct < 2; ++ct) {
    int ncol = n0 + wn + ct * 16 + l16;
    float bvv = bias[ncol];
#pragma unroll
    for (int rt = 0; rt < 4; ++rt)
#pragma unroll
      for (int r = 0; r < 4; ++r) {
        int m = m0 + wm + rt * 16 + quad * 4 + r;
        out[(size_t)m * 1024 + ncol] = acc[rt][ct][r] + bvv;
      }
  }
}

// ------------------------------------------------------------------ launch
extern "C" void kernel_launch(void* const* d_in, const int* in_sizes, int n_in,
                              void* d_out, int out_size, void* d_ws, size_t ws_size,
                              hipStream_t stream) {
  const float* query = (const float*)d_in[0];
  const float* key   = (const float*)d_in[1];
  const float* value = (const float*)d_in[2];
  const float* Wq = (const float*)d_in[3];
  const float* bq = (const float*)d_in[4];
  const float* Wk = (const float*)d_in[5];
  const float* bk = (const float*)d_in[6];
  const float* Wv = (const float*)d_in[7];
  const float* bv = (const float*)d_in[8];
  const float* Wo = (const float*)d_in[9];
  const float* bo = (const float*)d_in[10];
  float* out = (float*)d_out;

  // workspace layout (u16 elements): total 28M u16 = 56 MB
  u16* WT = (u16*)d_ws;              // 4 x 1M  (Wq_t, Wk_t, Wv_t, Wo_t)
  u16* QN = WT + 4 * 1048576;        // 4M  natural [b,s,1024] (pre-scaled by CSC)
  u16* KN = QN + 4194304;            // 4M  natural [b,s,1024]
  u16* VT = KN + 4194304;            // 4M  [b,h,d,s]
  u16* XB = VT + 4194304;            // 3 x 4M bf16 copies of q,k,v
  u16* AO = XB;                      // attn out aliases XB (dead by then)

  prep<<<dim3(13312), 256, 0, stream>>>(query, key, value, Wq, Wk, Wv, Wo, XB, WT);
  qkv_gemm<<<dim3(256, 3), 256, 0, stream>>>(XB, WT, bq, bk, bv, QN, KN, VT);
  attn11<<<dim3(16, 16, 2), 512, 0, stream>>>(QN, KN, VT, AO);
  oproj_gemm<<<dim3(512), 256, 0, stream>>>(AO, WT + 3 * 1048576, bo, out);
}